// Round 1
// baseline (187.858 us; speedup 1.0000x reference)
//
#include <hip/hip_runtime.h>

constexpr int Bn  = 1024;
constexpr int Tn  = 8192;
constexpr int Wn  = 2048;   // NUM_WORDS
constexpr int TPB = 1024;

// Per-position rule evaluation (matches the vectorized reference exactly):
//   INIT_TOKENS  = {94,122,100,92,43,27} -> INIT_DURS {2,3,2,2,5,5}
//   RATIO_TOKENS = {44,28,29,27,121,43}
__device__ __forceinline__ void rule_eval(float dp, float dpn, int tok, bool valid_next,
                                          float& g1, float& g2, float& sa) {
  float expected;
  bool in_init = true;
  switch (tok) {
    case 94:  expected = 2.f; break;
    case 122: expected = 3.f; break;
    case 100: expected = 2.f; break;
    case 92:  expected = 2.f; break;
    case 43:  expected = 5.f; break;
    case 27:  expected = 5.f; break;
    default:  expected = 0.f; in_init = false; break;
  }
  float t1 = dp - expected;
  bool fire1 = in_init && (t1 > 0.f);
  g1 = fire1 ? t1 : 0.f;
  bool in_ratio = (tok == 44) | (tok == 28) | (tok == 29) |
                  (tok == 27) | (tok == 121) | (tok == 43);
  bool fire2 = in_ratio && valid_next && (3.f * dp > dpn);
  g2 = fire2 ? (dp - dpn * (1.f / 3.f)) : 0.f;
  sa = fire2 ? g2 : (fire1 ? g1 : 0.f);
}

__device__ __forceinline__ float wave_reduce(float v) {
  #pragma unroll
  for (int o = 32; o > 0; o >>= 1) v += __shfl_down(v, o, 64);
  return v;
}

__global__ __launch_bounds__(TPB) void loss_kernel(
    const float* __restrict__ dur_pred, const float* __restrict__ dur_gt,
    const int* __restrict__ ph2word, const int* __restrict__ txt,
    double* __restrict__ acc)
{
  __shared__ float wp[Wn];
  __shared__ float wg[Wn];
  __shared__ float sacc[5];   // pdur_s, rules_s, sp, sg, wd_s

  const int row = blockIdx.x;
  const size_t roff = (size_t)row * Tn;
  const float* __restrict__ dpr = dur_pred + roff;
  const float* __restrict__ dgr = dur_gt + roff;
  const int*   __restrict__ pwr = ph2word + roff;
  const int*   __restrict__ tkr = txt + roff;

  for (int i = threadIdx.x; i < Wn; i += TPB) { wp[i] = 0.f; wg[i] = 0.f; }
  if (threadIdx.x < 5) sacc[threadIdx.x] = 0.f;
  __syncthreads();

  float pdur_s = 0.f, rules_s = 0.f, sp = 0.f, sg = 0.f;

  #pragma unroll
  for (int c = 0; c < 2; ++c) {
    const int base = c * (Tn / 2) + threadIdx.x * 4;

    float4 dp4 = *reinterpret_cast<const float4*>(dpr + base);
    float4 dg4 = *reinterpret_cast<const float4*>(dgr + base);
    int4   pw4 = *reinterpret_cast<const int4*>(pwr + base);
    int4   tk4 = *reinterpret_cast<const int4*>(tkr + base);

    const bool last = (base + 4 >= Tn);   // only thread 1023 in chunk c==1

    float dpx[6];
    dpx[0] = dp4.x; dpx[1] = dp4.y; dpx[2] = dp4.z; dpx[3] = dp4.w;
    dpx[4] = last ? 0.f : dpr[base + 4];
    dpx[5] = (base + 5 < Tn) ? dpr[base + 5] : 0.f;
    int tkx[5];
    tkx[0] = tk4.x; tkx[1] = tk4.y; tkx[2] = tk4.z; tkx[3] = tk4.w;
    tkx[4] = last ? -1 : tkr[base + 4];

    float g1[5], g2[5], sa[5];
    #pragma unroll
    for (int j = 0; j < 5; ++j) {
      int i = base + j;
      rule_eval(dpx[j], dpx[j + 1], tkx[j], i < Tn - 1, g1[j], g2[j], sa[j]);
    }

    float dgl[4] = {dg4.x, dg4.y, dg4.z, dg4.w};

    #pragma unroll
    for (int j = 0; j < 4; ++j) {
      int i = base + j;
      float dp = dpx[j];
      float add = (i < Tn - 1) ? (g1[j + 1] + g2[j + 1]) : 0.f;
      float dr = dp - sa[j] + add;            // dur_rules[i]
      float lp = __logf(dp + 1.f);
      float dlr = lp - __logf(dr + 1.f);
      rules_s += dlr * dlr;
      float dlg = lp - __logf(dgl[j] + 1.f);
      pdur_s += dlg * dlg;
      sp += fmaxf(dp, 0.f);
      sg += dgl[j];
    }

    // word segment sums: ph2word sorted per row -> run-compress, LDS atomics
    int pwl[4] = {pw4.x, pw4.y, pw4.z, pw4.w};
    int curw = pwl[0];
    float ap = 0.f, ag = 0.f;
    #pragma unroll
    for (int j = 0; j < 4; ++j) {
      if (pwl[j] != curw) {
        atomicAdd(&wp[curw], ap);
        atomicAdd(&wg[curw], ag);
        curw = pwl[j]; ap = 0.f; ag = 0.f;
      }
      ap += fmaxf(dpx[j], 0.f);
      ag += dgl[j];
    }
    atomicAdd(&wp[curw], ap);
    atomicAdd(&wg[curw], ag);
  }

  __syncthreads();

  // word-duration loss over words 1..Wn-1 (segment 0 dropped)
  float wd_s = 0.f;
  #pragma unroll
  for (int w = threadIdx.x; w < Wn; w += TPB) {
    if (w != 0) {
      float d = __logf(wp[w] + 1.f) - __logf(wg[w] + 1.f);
      wd_s += d * d;
    }
  }

  pdur_s  = wave_reduce(pdur_s);
  rules_s = wave_reduce(rules_s);
  sp      = wave_reduce(sp);
  sg      = wave_reduce(sg);
  wd_s    = wave_reduce(wd_s);
  if ((threadIdx.x & 63) == 0) {
    atomicAdd(&sacc[0], pdur_s);
    atomicAdd(&sacc[1], rules_s);
    atomicAdd(&sacc[2], sp);
    atomicAdd(&sacc[3], sg);
    atomicAdd(&sacc[4], wd_s);
  }
  __syncthreads();

  if (threadIdx.x == 0) {
    float ds = __logf(sacc[2] + 1.f) - __logf(sacc[3] + 1.f);
    double total = 0.6 * (double)sacc[0] / ((double)Bn * (double)Tn)
                 + 0.3 * (double)sacc[1] / ((double)Bn * (double)Tn)
                 + 0.3 * (double)sacc[4] / ((double)Bn * (double)(Wn - 1))
                 + 0.1 * (double)(ds * ds) / (double)Bn;
    atomicAdd(acc, total);
  }
}

__global__ void finalize_kernel(const double* __restrict__ acc, float* __restrict__ out) {
  out[0] = (float)(*acc);
}

extern "C" void kernel_launch(void* const* d_in, const int* in_sizes, int n_in,
                              void* d_out, int out_size, void* d_ws, size_t ws_size,
                              hipStream_t stream) {
  const float* dur_pred = (const float*)d_in[0];
  const float* dur_gt   = (const float*)d_in[1];
  const int*   ph2word  = (const int*)d_in[2];
  const int*   txt      = (const int*)d_in[3];
  double* acc = (double*)d_ws;

  hipMemsetAsync(d_ws, 0, sizeof(double), stream);
  loss_kernel<<<Bn, TPB, 0, stream>>>(dur_pred, dur_gt, ph2word, txt, acc);
  finalize_kernel<<<1, 1, 0, stream>>>(acc, (float*)d_out);
}